// Round 4
// baseline (229.229 us; speedup 1.0000x reference)
//
#include <hip/hip_runtime.h>
#include <hip/hip_bf16.h>

typedef unsigned short u16;
typedef unsigned int u32;
typedef __attribute__((ext_vector_type(8))) short bf16x8;
typedef __attribute__((ext_vector_type(4))) float f32x4;

#define MFMA_BF16(a, b, c) __builtin_amdgcn_mfma_f32_16x16x32_bf16((a), (b), (c), 0, 0, 0)

__device__ __forceinline__ u16 f2bf(float f) {
    u32 u;
    __builtin_memcpy(&u, &f, 4);
    u += 0x7fffu + ((u >> 16) & 1u);
    return (u16)(u >> 16);
}

__device__ __forceinline__ void glds16(const void* g, void* l) {
    __builtin_amdgcn_global_load_lds(
        (__attribute__((address_space(1))) void*)(g),
        (__attribute__((address_space(3))) void*)(l),
        16, 0, 0);
}

// ---------------------------------------------------------------------------
// f32 -> bf16 elementwise convert; 8 elements per thread.
// ---------------------------------------------------------------------------
__global__ __launch_bounds__(256) void f32_to_bf16(const float* __restrict__ in,
                                                   u16* __restrict__ out) {
    const int i = blockIdx.x * 256 + threadIdx.x;
    const float4* p = (const float4*)in;
    float4 a = p[i * 2], b = p[i * 2 + 1];
    ushort4 lo, hi;
    lo.x = f2bf(a.x); lo.y = f2bf(a.y); lo.z = f2bf(a.z); lo.w = f2bf(a.w);
    hi.x = f2bf(b.x); hi.y = f2bf(b.y); hi.z = f2bf(b.z); hi.w = f2bf(b.w);
    *(ushort4*)&out[i * 8] = lo;
    *(ushort4*)&out[i * 8 + 4] = hi;
}

// ---------------------------------------------------------------------------
// Weight transpose + f32->bf16: in f32 [K][N] -> out bf16 [N][K]
// grid: (N/64, K/64), block 256
// ---------------------------------------------------------------------------
__global__ __launch_bounds__(256) void transpose_k(const float* __restrict__ in,
                                                   u16* __restrict__ out,
                                                   int K, int N) {
    __shared__ u16 tl[64][68];
    const int tid = threadIdx.x;
    const int n0 = blockIdx.x * 64, k0 = blockIdx.y * 64;
    #pragma unroll
    for (int it = 0; it < 4; ++it) {
        int idx = tid + it * 256;
        int r = idx >> 4, c4 = (idx & 15) * 4;
        float4 v = *(const float4*)&in[(size_t)(k0 + r) * N + n0 + c4];
        tl[r][c4 + 0] = f2bf(v.x); tl[r][c4 + 1] = f2bf(v.y);
        tl[r][c4 + 2] = f2bf(v.z); tl[r][c4 + 3] = f2bf(v.w);
    }
    __syncthreads();
    #pragma unroll
    for (int it = 0; it < 4; ++it) {
        int idx = tid + it * 256;
        int r = idx >> 4, c4 = (idx & 15) * 4;
        ushort4 v;
        v.x = tl[c4 + 0][r]; v.y = tl[c4 + 1][r];
        v.z = tl[c4 + 2][r]; v.w = tl[c4 + 3][r];
        *(ushort4*)&out[(size_t)(n0 + r) * K + k0 + c4] = v;
    }
}

// ---------------------------------------------------------------------------
// bf16 transpose for V: reads V band from natural kqv [4096][3072]
// (cols 2048 + h*64 ..) -> out [BH][D=64][T=2048]. grid (T/64, BH), block 256.
// ---------------------------------------------------------------------------
__global__ __launch_bounds__(256) void transpose_v(const u16* __restrict__ kqv,
                                                   u16* __restrict__ out) {
    __shared__ u16 tl[64][72];
    const int tid = threadIdx.x;
    const int t0 = blockIdx.x * 64;
    const int bh = blockIdx.y;
    const int b = bh >> 4, hh = bh & 15;
    const u16* ip = kqv + (size_t)b * 2048 * 3072 + 2048 + hh * 64;
    u16* op = out + (size_t)bh * 64 * 2048;
    #pragma unroll
    for (int it = 0; it < 2; ++it) {
        int idx = tid + it * 256;
        int r = idx >> 3, c8 = (idx & 7) * 8;
        *(bf16x8*)&tl[r][c8] = *(const bf16x8*)&ip[(size_t)(t0 + r) * 3072 + c8];
    }
    __syncthreads();
    #pragma unroll
    for (int it = 0; it < 2; ++it) {
        int idx = tid + it * 256;
        int d = idx >> 3, c8 = (idx & 7) * 8;
        ushort4 v0, v1;
        v0.x = tl[c8 + 0][d]; v0.y = tl[c8 + 1][d];
        v0.z = tl[c8 + 2][d]; v0.w = tl[c8 + 3][d];
        v1.x = tl[c8 + 4][d]; v1.y = tl[c8 + 5][d];
        v1.z = tl[c8 + 6][d]; v1.w = tl[c8 + 7][d];
        *(ushort4*)&op[(size_t)d * 2048 + t0 + c8] = v0;
        *(ushort4*)&op[(size_t)d * 2048 + t0 + c8 + 4] = v1;
    }
}

// ---------------------------------------------------------------------------
// QKV GEMM, 2-phase double-buffered (T3-minimum): C[4096,3072] natural bf16.
// BM=BN=128, BK=32, 4 waves 2x2. Next K-tile staged via glds16 BEFORE the
// current tile's ds_read+MFMA; ONE barrier/iter. LDS chunk swizzle via
// pre-swizzled glds16 SOURCE (linear dest, rule 21); read side same XOR.
// K cols (<1024) pre-scaled by log2(e)/sqrt(64). LDS 32 KB -> 3 blocks/CU.
// ---------------------------------------------------------------------------
__global__ __launch_bounds__(256) void gemm_qkv(const u16* __restrict__ A,
                                                const u16* __restrict__ BT,
                                                const float* __restrict__ bias,
                                                u16* __restrict__ out) {
    __shared__ u16 As[2][128 * 32];
    __shared__ u16 Bs[2][128 * 32];
    const int tid = threadIdx.x;
    const int w = tid >> 6, lane = tid & 63;
    const int c = lane & 15, qd = lane >> 4;
    const int wm = (w >> 1) * 64, wn = (w & 1) * 64;
    const int bm = blockIdx.x * 128, bn = blockIdx.y * 128;
    const int K = 1024;

    f32x4 acc[4][4];
    #pragma unroll
    for (int mt = 0; mt < 4; ++mt)
        #pragma unroll
        for (int nt = 0; nt < 4; ++nt)
            acc[mt][nt] = (f32x4){0.f, 0.f, 0.f, 0.f};

    // staging: thread -> (row = tid>>2 [+64], src chunk swizzled by (row>>1)&3)
    const int srow = tid >> 2;
    const int schk8 = ((tid & 3) ^ ((tid >> 3) & 3)) * 8;
    const u16* aP = A + (size_t)(bm + srow) * K + schk8;
    const u16* bP = BT + (size_t)(bn + srow) * K + schk8;
    const int rk = (c >> 1) & 3;          // read-side xor key

    // prologue: stage K-tile 0 into buffer 0
    glds16(aP, &As[0][tid * 8]);
    glds16(aP + 64 * K, &As[0][2048 + tid * 8]);
    glds16(bP, &Bs[0][tid * 8]);
    glds16(bP + 64 * K, &Bs[0][2048 + tid * 8]);
    __syncthreads();

    for (int kk = 0; kk < K; kk += 32) {
        const int cur = (kk >> 5) & 1;
        if (kk + 32 < K) {               // prefetch next K-tile into other buf
            const int nb = cur ^ 1;
            glds16(aP + kk + 32, &As[nb][tid * 8]);
            glds16(aP + kk + 32 + 64 * K, &As[nb][2048 + tid * 8]);
            glds16(bP + kk + 32, &Bs[nb][tid * 8]);
            glds16(bP + kk + 32 + 64 * K, &Bs[nb][2048 + tid * 8]);
        }
        bf16x8 af[4], bfr[4];
        #pragma unroll
        for (int mt = 0; mt < 4; ++mt)
            af[mt] = *(const bf16x8*)&As[cur][(wm + mt * 16 + c) * 32 + ((qd ^ rk) << 3)];
        #pragma unroll
        for (int nt = 0; nt < 4; ++nt)
            bfr[nt] = *(const bf16x8*)&Bs[cur][(wn + nt * 16 + c) * 32 + ((qd ^ rk) << 3)];
        #pragma unroll
        for (int mt = 0; mt < 4; ++mt)
            #pragma unroll
            for (int nt = 0; nt < 4; ++nt)
                acc[mt][nt] = MFMA_BF16(af[mt], bfr[nt], acc[mt][nt]);
        __syncthreads();                 // drains prefetch vmcnt + read lgkm
    }

    #pragma unroll
    for (int nt = 0; nt < 4; ++nt) {
        const int coln = bn + wn + nt * 16 + c;
        const float bv = bias[coln];
        // fold attention scale log2(e)/sqrt(64) into K (cols < 1024)
        const float kscl = (coln < 1024) ? 0.18033688f : 1.0f;
        #pragma unroll
        for (int mt = 0; mt < 4; ++mt)
            #pragma unroll
            for (int r = 0; r < 4; ++r) {
                const int row = bm + wm + mt * 16 + qd * 4 + r;
                out[(size_t)row * 3072 + coln] = f2bf((acc[mt][nt][r] + bv) * kscl);
            }
    }
}

// ---------------------------------------------------------------------------
// Proj GEMM: C[4096,1024] f32 = A[4096,1024]*BT[1024,1024]^T + bias.
// BM=128, BN=64 -> grid 32x16 = 512 blocks = 2 blocks/CU. 4 waves 4Mx1N.
// Same dbuf + swizzle structure as gemm_qkv. LDS 24 KB.
// ---------------------------------------------------------------------------
__global__ __launch_bounds__(256) void gemm_proj(const u16* __restrict__ A,
                                                 const u16* __restrict__ BT,
                                                 const float* __restrict__ bias,
                                                 float* __restrict__ outf) {
    __shared__ u16 As[2][128 * 32];
    __shared__ u16 Bs[2][64 * 32];
    const int tid = threadIdx.x;
    const int w = tid >> 6, lane = tid & 63;
    const int c = lane & 15, qd = lane >> 4;
    const int wm = w * 32;
    const int bm = blockIdx.x * 128, bn = blockIdx.y * 64;
    const int K = 1024;

    f32x4 acc[2][4];
    #pragma unroll
    for (int mt = 0; mt < 2; ++mt)
        #pragma unroll
        for (int nt = 0; nt < 4; ++nt)
            acc[mt][nt] = (f32x4){0.f, 0.f, 0.f, 0.f};

    const int srow = tid >> 2;
    const int schk8 = ((tid & 3) ^ ((tid >> 3) & 3)) * 8;
    const u16* aP = A + (size_t)(bm + srow) * K + schk8;
    const u16* bP = BT + (size_t)(bn + srow) * K + schk8;
    const int rk = (c >> 1) & 3;

    glds16(aP, &As[0][tid * 8]);
    glds16(aP + 64 * K, &As[0][2048 + tid * 8]);
    glds16(bP, &Bs[0][tid * 8]);
    __syncthreads();

    for (int kk = 0; kk < K; kk += 32) {
        const int cur = (kk >> 5) & 1;
        if (kk + 32 < K) {
            const int nb = cur ^ 1;
            glds16(aP + kk + 32, &As[nb][tid * 8]);
            glds16(aP + kk + 32 + 64 * K, &As[nb][2048 + tid * 8]);
            glds16(bP + kk + 32, &Bs[nb][tid * 8]);
        }
        bf16x8 af[2], bfr[4];
        #pragma unroll
        for (int mt = 0; mt < 2; ++mt)
            af[mt] = *(const bf16x8*)&As[cur][(wm + mt * 16 + c) * 32 + ((qd ^ rk) << 3)];
        #pragma unroll
        for (int nt = 0; nt < 4; ++nt)
            bfr[nt] = *(const bf16x8*)&Bs[cur][(nt * 16 + c) * 32 + ((qd ^ rk) << 3)];
        #pragma unroll
        for (int mt = 0; mt < 2; ++mt)
            #pragma unroll
            for (int nt = 0; nt < 4; ++nt)
                acc[mt][nt] = MFMA_BF16(af[mt], bfr[nt], acc[mt][nt]);
        __syncthreads();
    }

    #pragma unroll
    for (int nt = 0; nt < 4; ++nt) {
        const int coln = bn + nt * 16 + c;
        const float bv = bias[coln];
        #pragma unroll
        for (int mt = 0; mt < 2; ++mt)
            #pragma unroll
            for (int r = 0; r < 4; ++r) {
                const int row = bm + wm + mt * 16 + qd * 4 + r;
                outf[(size_t)row * 1024 + coln] = acc[mt][nt][r] + bv;
            }
    }
}

// ---------------------------------------------------------------------------
// MFMA flash attention v7. wei = K@Q^T (K rows = queries). K pre-scaled.
// 1024 blocks (32 ib x 32 bh), one 64-row i-block per block, longest-first.
// v6 was LDS-capped at 3 blocks/CU (42.5KB), chain only 3-way overlapped
// (VALUBusy 49%, MfmaUtil 15%). v7: Q fragments read DIRECT global->regs
// (Q per-XCD set ~1MB, L2/L1-resident; 4x wave dup is ~550MB L2 = within
// per-XCD budget) -> LDS 25.9KB (V dbuf + Ps only) -> 5+ blocks/CU,
// launch_bounds(256,5) caps VGPR<=102.
// l computed by ones-B MFMA (lacc = mfma(pf, 1s, lacc)): D rows (qd*4+r)
// match oacc layout -> no l VALU adds, no epilogue shfl reduce, no red[];
// denominator uses same rounded-bf16 P as numerator.
// s_setprio(1) around MFMA clusters (T5). P pack via round+v_perm.
// ---------------------------------------------------------------------------
__global__ __launch_bounds__(256, 5) void attn_kernel(const u16* __restrict__ kqv,
                                                      const u16* __restrict__ vtbuf,
                                                      u16* __restrict__ outb) {
    __shared__ __align__(16) u16 Vb[2][64 * 64];
    __shared__ __align__(16) u16 Ps[4][16 * 72];

    const int tid = threadIdx.x;
    const int w = tid >> 6, lane = tid & 63;
    const int c = lane & 15, qd = lane >> 4;
    // decode: xcd = f&7 hosts bh in [xcd*4, xcd*4+4); ib descending in time
    const int f = blockIdx.x;
    const int bh = (f & 7) * 4 + ((f >> 3) & 3);
    const int ib = 31 - (f >> 5);       // longest blocks dispatch first
    const int b = bh >> 4, hh = bh & 15;
    const u16* kp = kqv + (size_t)b * 2048 * 3072 + hh * 64;          // k band
    const u16* qp = kqv + (size_t)b * 2048 * 3072 + 1024 + hh * 64;   // q band
    const u16* vp = vtbuf + (size_t)bh * (64 * 2048);
    u16* op = outb + (size_t)b * (2048 * 1024) + hh * 64;
    const f32x4 zero4 = {0.f, 0.f, 0.f, 0.f};

    // V staging geometry: thread covers slots (w*128+lane) and (+64)
    const int slot0 = w * 128 + lane;
    const int slot1 = slot0 + 64;
    const int r0 = slot0 >> 3, r1 = slot1 >> 3;            // r1 = r0 + 8
    const int c8g = ((lane & 7) ^ ((lane >> 3) & 7)) * 8;  // swizzled src col
    const int swz = (c & 7);                               // read-side xor key

    const int nj = ib + 1;
    const int iw = ib * 64 + w * 16;                       // wave's 16 i-rows

    // K fragments direct from global (2 KB/wave, read once per block)
    bf16x8 kf[2];
    #pragma unroll
    for (int kt = 0; kt < 2; ++kt)
        kf[kt] = *(const bf16x8*)&kp[(size_t)(iw + c) * 3072 + kt * 32 + qd * 8];

    // all-ones bf16 B-fragment for the l row-sum MFMA
    bf16x8 ones;
    #pragma unroll
    for (int e = 0; e < 8; ++e) ones[e] = (short)0x3F80;

    f32x4 oacc[4];
    #pragma unroll
    for (int nt = 0; nt < 4; ++nt)
        oacc[nt] = zero4;
    f32x4 lacc = zero4;

    // per-lane Q base: row offset c, col slice qd*8
    const u16* qlp = qp + (size_t)c * 3072 + qd * 8;

    // prologue: stage V tile 0 into buffer 0
    glds16(vp + (size_t)r0 * 2048 + c8g, &Vb[0][slot0 * 8]);
    glds16(vp + (size_t)r1 * 2048 + c8g, &Vb[0][slot1 * 8]);
    __syncthreads();

    for (int jj = 0; jj < nj; ++jj) {
        const int cur = jj & 1;
        const int j0 = jj * 64;

        // Q fragments direct from global (critical path: issue first)
        bf16x8 qf[4][2];
        #pragma unroll
        for (int jt = 0; jt < 4; ++jt)
            #pragma unroll
            for (int kt = 0; kt < 2; ++kt)
                qf[jt][kt] = *(const bf16x8*)&qlp[(size_t)(j0 + jt * 16) * 3072 + kt * 32];

        if (jj + 1 < nj) {              // async-prefetch next V tile
            const int jn = (jj + 1) * 64;
            const int nb = cur ^ 1;
            glds16(vp + (size_t)r0 * 2048 + jn + c8g, &Vb[nb][slot0 * 8]);
            glds16(vp + (size_t)r1 * 2048 + jn + c8g, &Vb[nb][slot1 * 8]);
        }

        // S^T[j][i]: A = Q rows j (4 jt), B = kf (wave's 16 i-rows)
        f32x4 sacc[4];
        __builtin_amdgcn_s_setprio(1);
        #pragma unroll
        for (int jt = 0; jt < 4; ++jt) {
            f32x4 s0 = zero4;
            s0 = MFMA_BF16(qf[jt][0], kf[0], s0);
            s0 = MFMA_BF16(qf[jt][1], kf[1], s0);
            sacc[jt] = s0;
        }
        __builtin_amdgcn_s_setprio(0);

        if (jj == nj - 1) {   // diagonal tile: causal mask, valid iff j <= i
            #pragma unroll
            for (int jt = 0; jt < 4; ++jt)
                #pragma unroll
                for (int r = 0; r < 4; ++r) {
                    int j = j0 + jt * 16 + qd * 4 + r;
                    int i = iw + c;
                    if (j > i) sacc[jt][r] = -3.0e38f;
                }
        }

        // static-max softmax; pack P via round-half-up + v_perm (3 ops / 2 vals)
        #pragma unroll
        for (int jt = 0; jt < 4; ++jt) {
            float p0 = exp2f(sacc[jt][0]);
            float p1 = exp2f(sacc[jt][1]);
            float p2 = exp2f(sacc[jt][2]);
            float p3 = exp2f(sacc[jt][3]);
            u32 b0, b1, b2, b3;
            __builtin_memcpy(&b0, &p0, 4);
            __builtin_memcpy(&b1, &p1, 4);
            __builtin_memcpy(&b2, &p2, 4);
            __builtin_memcpy(&b3, &p3, 4);
            uint2 pk;
            pk.x = __builtin_amdgcn_perm(b1 + 0x8000u, b0 + 0x8000u, 0x07060302u);
            pk.y = __builtin_amdgcn_perm(b3 + 0x8000u, b2 + 0x8000u, 0x07060302u);
            *(uint2*)&Ps[w][c * 72 + jt * 16 + qd * 4] = pk;
        }

        // O[i][d] += P[i][j] * V[j][d];  l[i] += sum_j P[i][j] via ones-MFMA
        __builtin_amdgcn_s_setprio(1);
        #pragma unroll
        for (int kt = 0; kt < 2; ++kt) {
            bf16x8 pf = *(const bf16x8*)&Ps[w][c * 72 + kt * 32 + qd * 8];
            lacc = MFMA_BF16(pf, ones, lacc);
            #pragma unroll
            for (int nt = 0; nt < 4; ++nt) {
                bf16x8 vf = *(const bf16x8*)&Vb[cur][(nt * 16 + c) * 64 + (((kt * 4 + qd) ^ swz) << 3)];
                oacc[nt] = MFMA_BF16(pf, vf, oacc[nt]);
            }
        }
        __builtin_amdgcn_s_setprio(0);
        __syncthreads();   // drains prefetch glds; all reads of cur done
    }

    // epilogue: l rows (qd*4+r) match oacc rows directly — no reduce needed
    #pragma unroll
    for (int r = 0; r < 4; ++r) {
        const int irow = iw + qd * 4 + r;
        const float inv = 1.0f / lacc[r];
        #pragma unroll
        for (int nt = 0; nt < 4; ++nt)
            op[(size_t)irow * 1024 + nt * 16 + c] = f2bf(oacc[nt][r] * inv);
    }
}

// ---------------------------------------------------------------------------
// ws plan (peak 40 MiB):
//   kqv@0 (24M, natural [4096][3072] bf16)  vtr@24M (8M)
//   wt_attn@32M (6M, dead after gemm_qkv)  abuf@32M (8M, after wt_attn dead)
//   wt_proj@0 (2M, kqv dead after attn)
//   xb (bf16 x) staged in d_out (f32 out = 16 MB); dead before proj gemm.
// ---------------------------------------------------------------------------
extern "C" void kernel_launch(void* const* d_in, const int* in_sizes, int n_in,
                              void* d_out, int out_size, void* d_ws, size_t ws_size,
                              hipStream_t stream) {
    const void *px = nullptr, *paw = nullptr, *pab = nullptr, *ppw = nullptr, *ppb = nullptr;
    for (int i = 0; i < n_in; ++i) {
        switch (in_sizes[i]) {
            case 4194304: px  = d_in[i]; break;  // x [2,2048,1024] f32
            case 3145728: paw = d_in[i]; break;  // c_attn_w [1024,3072] f32
            case 3072:    pab = d_in[i]; break;  // c_attn_b f32
            case 1048576: ppw = d_in[i]; break;  // c_proj_w [1024,1024] f32
            case 1024:    ppb = d_in[i]; break;  // c_proj_b f32
        }
    }
    if (!px || !paw || !pab || !ppw || !ppb) return;

    char* ws = (char*)d_ws;
    u16* kqv     = (u16*)(ws);                 // [4096,3072] bf16  24 MB
    u16* vtr     = (u16*)(ws + 25165824);      // [2,16,64,2048]     8 MB
    u16* wt_attn = (u16*)(ws + 33554432);      // [3072,1024]        6 MB
    u16* abuf    = (u16*)(ws + 33554432);      // [4096,1024] bf16   8 MB (wt_attn dead)
    u16* wt_proj = (u16*)(ws);                 // [1024,1024]        2 MB (kqv dead)
    float* out   = (float*)d_out;              // [4096,1024] f32
    u16* xb      = (u16*)d_out;                // bf16 x staged in d_out

    f32_to_bf16<<<2048, 256, 0, stream>>>((const float*)px, xb);
    transpose_k<<<dim3(48, 16), 256, 0, stream>>>((const float*)paw, wt_attn, 1024, 3072);
    gemm_qkv<<<dim3(32, 24), 256, 0, stream>>>(xb, wt_attn, (const float*)pab, kqv);
    transpose_v<<<dim3(32, 32), 256, 0, stream>>>(kqv, vtr);
    attn_kernel<<<dim3(1024), 256, 0, stream>>>(kqv, vtr, abuf);
    transpose_k<<<dim3(16, 16), 256, 0, stream>>>((const float*)ppw, wt_proj, 1024, 1024);
    gemm_proj<<<dim3(32, 16), 256, 0, stream>>>(abuf, wt_proj, (const float*)ppb, out);
}

// Round 5
// 183.004 us; speedup vs baseline: 1.2526x; 1.2526x over previous
//
#include <hip/hip_runtime.h>
#include <hip/hip_bf16.h>

typedef unsigned short u16;
typedef unsigned int u32;
typedef __attribute__((ext_vector_type(8))) short bf16x8;
typedef __attribute__((ext_vector_type(4))) float f32x4;

#define MFMA_BF16(a, b, c) __builtin_amdgcn_mfma_f32_16x16x32_bf16((a), (b), (c), 0, 0, 0)

__device__ __forceinline__ u16 f2bf(float f) {
    u32 u;
    __builtin_memcpy(&u, &f, 4);
    u += 0x7fffu + ((u >> 16) & 1u);
    return (u16)(u >> 16);
}

__device__ __forceinline__ void glds16(const void* g, void* l) {
    __builtin_amdgcn_global_load_lds(
        (__attribute__((address_space(1))) void*)(g),
        (__attribute__((address_space(3))) void*)(l),
        16, 0, 0);
}

// ---------------------------------------------------------------------------
// f32 -> bf16 elementwise convert; 8 elements per thread.
// ---------------------------------------------------------------------------
__global__ __launch_bounds__(256) void f32_to_bf16(const float* __restrict__ in,
                                                   u16* __restrict__ out) {
    const int i = blockIdx.x * 256 + threadIdx.x;
    const float4* p = (const float4*)in;
    float4 a = p[i * 2], b = p[i * 2 + 1];
    ushort4 lo, hi;
    lo.x = f2bf(a.x); lo.y = f2bf(a.y); lo.z = f2bf(a.z); lo.w = f2bf(a.w);
    hi.x = f2bf(b.x); hi.y = f2bf(b.y); hi.z = f2bf(b.z); hi.w = f2bf(b.w);
    *(ushort4*)&out[i * 8] = lo;
    *(ushort4*)&out[i * 8 + 4] = hi;
}

// ---------------------------------------------------------------------------
// Weight transpose + f32->bf16: in f32 [K][N] -> out bf16 [N][K]
// grid: (N/64, K/64), block 256
// ---------------------------------------------------------------------------
__global__ __launch_bounds__(256) void transpose_k(const float* __restrict__ in,
                                                   u16* __restrict__ out,
                                                   int K, int N) {
    __shared__ u16 tl[64][68];
    const int tid = threadIdx.x;
    const int n0 = blockIdx.x * 64, k0 = blockIdx.y * 64;
    #pragma unroll
    for (int it = 0; it < 4; ++it) {
        int idx = tid + it * 256;
        int r = idx >> 4, c4 = (idx & 15) * 4;
        float4 v = *(const float4*)&in[(size_t)(k0 + r) * N + n0 + c4];
        tl[r][c4 + 0] = f2bf(v.x); tl[r][c4 + 1] = f2bf(v.y);
        tl[r][c4 + 2] = f2bf(v.z); tl[r][c4 + 3] = f2bf(v.w);
    }
    __syncthreads();
    #pragma unroll
    for (int it = 0; it < 4; ++it) {
        int idx = tid + it * 256;
        int r = idx >> 4, c4 = (idx & 15) * 4;
        ushort4 v;
        v.x = tl[c4 + 0][r]; v.y = tl[c4 + 1][r];
        v.z = tl[c4 + 2][r]; v.w = tl[c4 + 3][r];
        *(ushort4*)&out[(size_t)(n0 + r) * K + k0 + c4] = v;
    }
}

// ---------------------------------------------------------------------------
// bf16 transpose for V: reads V band from natural kqv [4096][3072]
// (cols 2048 + h*64 ..) -> out [BH][D=64][T=2048]. grid (T/64, BH), block 256.
// ---------------------------------------------------------------------------
__global__ __launch_bounds__(256) void transpose_v(const u16* __restrict__ kqv,
                                                   u16* __restrict__ out) {
    __shared__ u16 tl[64][72];
    const int tid = threadIdx.x;
    const int t0 = blockIdx.x * 64;
    const int bh = blockIdx.y;
    const int b = bh >> 4, hh = bh & 15;
    const u16* ip = kqv + (size_t)b * 2048 * 3072 + 2048 + hh * 64;
    u16* op = out + (size_t)bh * 64 * 2048;
    #pragma unroll
    for (int it = 0; it < 2; ++it) {
        int idx = tid + it * 256;
        int r = idx >> 3, c8 = (idx & 7) * 8;
        *(bf16x8*)&tl[r][c8] = *(const bf16x8*)&ip[(size_t)(t0 + r) * 3072 + c8];
    }
    __syncthreads();
    #pragma unroll
    for (int it = 0; it < 2; ++it) {
        int idx = tid + it * 256;
        int d = idx >> 3, c8 = (idx & 7) * 8;
        ushort4 v0, v1;
        v0.x = tl[c8 + 0][d]; v0.y = tl[c8 + 1][d];
        v0.z = tl[c8 + 2][d]; v0.w = tl[c8 + 3][d];
        v1.x = tl[c8 + 4][d]; v1.y = tl[c8 + 5][d];
        v1.z = tl[c8 + 6][d]; v1.w = tl[c8 + 7][d];
        *(ushort4*)&op[(size_t)d * 2048 + t0 + c8] = v0;
        *(ushort4*)&op[(size_t)d * 2048 + t0 + c8 + 4] = v1;
    }
}

// ---------------------------------------------------------------------------
// QKV GEMM, 2-phase double-buffered (T3-minimum): C[4096,3072] natural bf16.
// BM=BN=128, BK=32, 4 waves 2x2. Next K-tile staged via glds16 BEFORE the
// current tile's ds_read+MFMA; ONE barrier/iter. LDS chunk swizzle via
// pre-swizzled glds16 SOURCE (linear dest, rule 21); read side same XOR.
// K cols (<1024) pre-scaled by log2(e)/sqrt(64). LDS 32 KB -> 3 blocks/CU.
// ---------------------------------------------------------------------------
__global__ __launch_bounds__(256) void gemm_qkv(const u16* __restrict__ A,
                                                const u16* __restrict__ BT,
                                                const float* __restrict__ bias,
                                                u16* __restrict__ out) {
    __shared__ u16 As[2][128 * 32];
    __shared__ u16 Bs[2][128 * 32];
    const int tid = threadIdx.x;
    const int w = tid >> 6, lane = tid & 63;
    const int c = lane & 15, qd = lane >> 4;
    const int wm = (w >> 1) * 64, wn = (w & 1) * 64;
    const int bm = blockIdx.x * 128, bn = blockIdx.y * 128;
    const int K = 1024;

    f32x4 acc[4][4];
    #pragma unroll
    for (int mt = 0; mt < 4; ++mt)
        #pragma unroll
        for (int nt = 0; nt < 4; ++nt)
            acc[mt][nt] = (f32x4){0.f, 0.f, 0.f, 0.f};

    // staging: thread -> (row = tid>>2 [+64], src chunk swizzled by (row>>1)&3)
    const int srow = tid >> 2;
    const int schk8 = ((tid & 3) ^ ((tid >> 3) & 3)) * 8;
    const u16* aP = A + (size_t)(bm + srow) * K + schk8;
    const u16* bP = BT + (size_t)(bn + srow) * K + schk8;
    const int rk = (c >> 1) & 3;          // read-side xor key

    // prologue: stage K-tile 0 into buffer 0
    glds16(aP, &As[0][tid * 8]);
    glds16(aP + 64 * K, &As[0][2048 + tid * 8]);
    glds16(bP, &Bs[0][tid * 8]);
    glds16(bP + 64 * K, &Bs[0][2048 + tid * 8]);
    __syncthreads();

    for (int kk = 0; kk < K; kk += 32) {
        const int cur = (kk >> 5) & 1;
        if (kk + 32 < K) {               // prefetch next K-tile into other buf
            const int nb = cur ^ 1;
            glds16(aP + kk + 32, &As[nb][tid * 8]);
            glds16(aP + kk + 32 + 64 * K, &As[nb][2048 + tid * 8]);
            glds16(bP + kk + 32, &Bs[nb][tid * 8]);
            glds16(bP + kk + 32 + 64 * K, &Bs[nb][2048 + tid * 8]);
        }
        bf16x8 af[4], bfr[4];
        #pragma unroll
        for (int mt = 0; mt < 4; ++mt)
            af[mt] = *(const bf16x8*)&As[cur][(wm + mt * 16 + c) * 32 + ((qd ^ rk) << 3)];
        #pragma unroll
        for (int nt = 0; nt < 4; ++nt)
            bfr[nt] = *(const bf16x8*)&Bs[cur][(wn + nt * 16 + c) * 32 + ((qd ^ rk) << 3)];
        #pragma unroll
        for (int mt = 0; mt < 4; ++mt)
            #pragma unroll
            for (int nt = 0; nt < 4; ++nt)
                acc[mt][nt] = MFMA_BF16(af[mt], bfr[nt], acc[mt][nt]);
        __syncthreads();                 // drains prefetch vmcnt + read lgkm
    }

    #pragma unroll
    for (int nt = 0; nt < 4; ++nt) {
        const int coln = bn + wn + nt * 16 + c;
        const float bv = bias[coln];
        // fold attention scale log2(e)/sqrt(64) into K (cols < 1024)
        const float kscl = (coln < 1024) ? 0.18033688f : 1.0f;
        #pragma unroll
        for (int mt = 0; mt < 4; ++mt)
            #pragma unroll
            for (int r = 0; r < 4; ++r) {
                const int row = bm + wm + mt * 16 + qd * 4 + r;
                out[(size_t)row * 3072 + coln] = f2bf((acc[mt][nt][r] + bv) * kscl);
            }
    }
}

// ---------------------------------------------------------------------------
// Proj GEMM: C[4096,1024] f32 = A[4096,1024]*BT[1024,1024]^T + bias.
// BM=128, BN=64 -> grid 32x16 = 512 blocks = 2 blocks/CU. 4 waves 4Mx1N.
// Same dbuf + swizzle structure as gemm_qkv. LDS 24 KB.
// ---------------------------------------------------------------------------
__global__ __launch_bounds__(256) void gemm_proj(const u16* __restrict__ A,
                                                 const u16* __restrict__ BT,
                                                 const float* __restrict__ bias,
                                                 float* __restrict__ outf) {
    __shared__ u16 As[2][128 * 32];
    __shared__ u16 Bs[2][64 * 32];
    const int tid = threadIdx.x;
    const int w = tid >> 6, lane = tid & 63;
    const int c = lane & 15, qd = lane >> 4;
    const int wm = w * 32;
    const int bm = blockIdx.x * 128, bn = blockIdx.y * 64;
    const int K = 1024;

    f32x4 acc[2][4];
    #pragma unroll
    for (int mt = 0; mt < 2; ++mt)
        #pragma unroll
        for (int nt = 0; nt < 4; ++nt)
            acc[mt][nt] = (f32x4){0.f, 0.f, 0.f, 0.f};

    const int srow = tid >> 2;
    const int schk8 = ((tid & 3) ^ ((tid >> 3) & 3)) * 8;
    const u16* aP = A + (size_t)(bm + srow) * K + schk8;
    const u16* bP = BT + (size_t)(bn + srow) * K + schk8;
    const int rk = (c >> 1) & 3;

    glds16(aP, &As[0][tid * 8]);
    glds16(aP + 64 * K, &As[0][2048 + tid * 8]);
    glds16(bP, &Bs[0][tid * 8]);
    __syncthreads();

    for (int kk = 0; kk < K; kk += 32) {
        const int cur = (kk >> 5) & 1;
        if (kk + 32 < K) {
            const int nb = cur ^ 1;
            glds16(aP + kk + 32, &As[nb][tid * 8]);
            glds16(aP + kk + 32 + 64 * K, &As[nb][2048 + tid * 8]);
            glds16(bP + kk + 32, &Bs[nb][tid * 8]);
        }
        bf16x8 af[2], bfr[4];
        #pragma unroll
        for (int mt = 0; mt < 2; ++mt)
            af[mt] = *(const bf16x8*)&As[cur][(wm + mt * 16 + c) * 32 + ((qd ^ rk) << 3)];
        #pragma unroll
        for (int nt = 0; nt < 4; ++nt)
            bfr[nt] = *(const bf16x8*)&Bs[cur][(nt * 16 + c) * 32 + ((qd ^ rk) << 3)];
        #pragma unroll
        for (int mt = 0; mt < 2; ++mt)
            #pragma unroll
            for (int nt = 0; nt < 4; ++nt)
                acc[mt][nt] = MFMA_BF16(af[mt], bfr[nt], acc[mt][nt]);
        __syncthreads();
    }

    #pragma unroll
    for (int nt = 0; nt < 4; ++nt) {
        const int coln = bn + nt * 16 + c;
        const float bv = bias[coln];
        #pragma unroll
        for (int mt = 0; mt < 2; ++mt)
            #pragma unroll
            for (int r = 0; r < 4; ++r) {
                const int row = bm + wm + mt * 16 + qd * 4 + r;
                outf[(size_t)row * 1024 + coln] = acc[mt][nt][r] + bv;
            }
    }
}

// ---------------------------------------------------------------------------
// MFMA flash attention v8. wei = K@Q^T (K rows = queries). K pre-scaled.
// v7 post-mortem: Q direct-from-global put an L2 round-trip ON the per-tile
// critical path (VALUBusy 49->21, dur 43->90us). REVERTED: Q back in async
// double-buffered LDS (v6 structure, latency hidden behind prior tile).
// Kept validated v7 riders: l via ones-B MFMA (no VALU adds / no epilogue
// reduce / no red[]), v_perm P-pack, diagonal-only mask, setprio (T5).
// New: Ps stride 72 -> 64 with XOR swizzle (col ^ ((c&7)<<3), >=8B granule,
// consistent across uint2 write + b128 read; write 4cyc / read 8cyc =
// BW-minimal). LDS = 16384+16384+8192 = 40960 B EXACTLY -> 4 blocks/CU
// (was 42.5KB -> 3), launch_bounds(256,4).
// 1024 blocks (32 ib x 32 bh), longest-first, XCD-grouped bh decode.
// ---------------------------------------------------------------------------
__global__ __launch_bounds__(256, 4) void attn_kernel(const u16* __restrict__ kqv,
                                                      const u16* __restrict__ vtbuf,
                                                      u16* __restrict__ outb) {
    __shared__ __align__(16) u16 Qb[2][64 * 64];
    __shared__ __align__(16) u16 Vb[2][64 * 64];
    __shared__ __align__(16) u16 Ps[4][16 * 64];

    const int tid = threadIdx.x;
    const int w = tid >> 6, lane = tid & 63;
    const int c = lane & 15, qd = lane >> 4;
    // decode: xcd = f&7 hosts bh in [xcd*4, xcd*4+4); ib descending in time
    const int f = blockIdx.x;
    const int bh = (f & 7) * 4 + ((f >> 3) & 3);
    const int ib = 31 - (f >> 5);       // longest blocks dispatch first
    const int b = bh >> 4, hh = bh & 15;
    const u16* kp = kqv + (size_t)b * 2048 * 3072 + hh * 64;          // k band
    const u16* qp = kqv + (size_t)b * 2048 * 3072 + 1024 + hh * 64;   // q band
    const u16* vp = vtbuf + (size_t)bh * (64 * 2048);
    u16* op = outb + (size_t)b * (2048 * 1024) + hh * 64;
    const f32x4 zero4 = {0.f, 0.f, 0.f, 0.f};

    // staging geometry: thread covers slots (w*128+lane) and (+64); 8 rows/8 col8
    const int slot0 = w * 128 + lane;
    const int slot1 = slot0 + 64;
    const int r0 = slot0 >> 3, r1 = slot1 >> 3;            // r1 = r0 + 8
    const int c8g = ((lane & 7) ^ ((lane >> 3) & 7)) * 8;  // swizzled src col
    const int swz = (c & 7);                               // read-side xor key
    const int psw = (c & 7) << 3;                          // Ps xor key (u16 units)

    const int nj = ib + 1;
    const int iw = ib * 64 + w * 16;                       // wave's 16 i-rows

    // K fragments direct from global (2 KB/wave, read once per block)
    bf16x8 kf[2];
    #pragma unroll
    for (int kt = 0; kt < 2; ++kt)
        kf[kt] = *(const bf16x8*)&kp[(size_t)(iw + c) * 3072 + kt * 32 + qd * 8];

    // all-ones bf16 B-fragment for the l row-sum MFMA
    bf16x8 ones;
    #pragma unroll
    for (int e = 0; e < 8; ++e) ones[e] = (short)0x3F80;

    f32x4 oacc[4];
    #pragma unroll
    for (int nt = 0; nt < 4; ++nt)
        oacc[nt] = zero4;
    f32x4 lacc = zero4;

    // prologue: stage tile 0 into buffer 0
    glds16(qp + (size_t)r0 * 3072 + c8g, &Qb[0][slot0 * 8]);
    glds16(qp + (size_t)r1 * 3072 + c8g, &Qb[0][slot1 * 8]);
    glds16(vp + (size_t)r0 * 2048 + c8g, &Vb[0][slot0 * 8]);
    glds16(vp + (size_t)r1 * 2048 + c8g, &Vb[0][slot1 * 8]);
    __syncthreads();

    for (int jj = 0; jj < nj; ++jj) {
        const int cur = jj & 1;
        if (jj + 1 < nj) {              // async-prefetch next tile
            const int jn = (jj + 1) * 64;
            const int nb = cur ^ 1;
            glds16(qp + (size_t)(jn + r0) * 3072 + c8g, &Qb[nb][slot0 * 8]);
            glds16(qp + (size_t)(jn + r1) * 3072 + c8g, &Qb[nb][slot1 * 8]);
            glds16(vp + (size_t)r0 * 2048 + jn + c8g, &Vb[nb][slot0 * 8]);
            glds16(vp + (size_t)r1 * 2048 + jn + c8g, &Vb[nb][slot1 * 8]);
        }
        const int j0 = jj * 64;

        // S^T[j][i]: A = Q rows j (4 jt), B = kf (wave's 16 i-rows)
        bf16x8 qf[4][2];
        #pragma unroll
        for (int jt = 0; jt < 4; ++jt)
            #pragma unroll
            for (int kt = 0; kt < 2; ++kt)
                qf[jt][kt] = *(const bf16x8*)&Qb[cur][(jt * 16 + c) * 64 + (((kt * 4 + qd) ^ swz) << 3)];
        f32x4 sacc[4];
        __builtin_amdgcn_s_setprio(1);
        #pragma unroll
        for (int jt = 0; jt < 4; ++jt) {
            f32x4 s0 = zero4;
            s0 = MFMA_BF16(qf[jt][0], kf[0], s0);
            s0 = MFMA_BF16(qf[jt][1], kf[1], s0);
            sacc[jt] = s0;
        }
        __builtin_amdgcn_s_setprio(0);

        if (jj == nj - 1) {   // diagonal tile: causal mask, valid iff j <= i
            #pragma unroll
            for (int jt = 0; jt < 4; ++jt)
                #pragma unroll
                for (int r = 0; r < 4; ++r) {
                    int j = j0 + jt * 16 + qd * 4 + r;
                    int i = iw + c;
                    if (j > i) sacc[jt][r] = -3.0e38f;
                }
        }

        // static-max softmax; pack P via round-half-up + v_perm (3 ops / 2 vals)
        #pragma unroll
        for (int jt = 0; jt < 4; ++jt) {
            float p0 = exp2f(sacc[jt][0]);
            float p1 = exp2f(sacc[jt][1]);
            float p2 = exp2f(sacc[jt][2]);
            float p3 = exp2f(sacc[jt][3]);
            u32 b0, b1, b2, b3;
            __builtin_memcpy(&b0, &p0, 4);
            __builtin_memcpy(&b1, &p1, 4);
            __builtin_memcpy(&b2, &p2, 4);
            __builtin_memcpy(&b3, &p3, 4);
            uint2 pk;
            pk.x = __builtin_amdgcn_perm(b1 + 0x8000u, b0 + 0x8000u, 0x07060302u);
            pk.y = __builtin_amdgcn_perm(b3 + 0x8000u, b2 + 0x8000u, 0x07060302u);
            *(uint2*)&Ps[w][c * 64 + ((jt * 16 + qd * 4) ^ psw)] = pk;
        }

        // O[i][d] += P[i][j] * V[j][d];  l[i] += sum_j P[i][j] via ones-MFMA
        __builtin_amdgcn_s_setprio(1);
        #pragma unroll
        for (int kt = 0; kt < 2; ++kt) {
            bf16x8 pf = *(const bf16x8*)&Ps[w][c * 64 + ((kt * 32 + qd * 8) ^ psw)];
            lacc = MFMA_BF16(pf, ones, lacc);
            #pragma unroll
            for (int nt = 0; nt < 4; ++nt) {
                bf16x8 vf = *(const bf16x8*)&Vb[cur][(nt * 16 + c) * 64 + (((kt * 4 + qd) ^ swz) << 3)];
                oacc[nt] = MFMA_BF16(pf, vf, oacc[nt]);
            }
        }
        __builtin_amdgcn_s_setprio(0);
        __syncthreads();   // drains prefetch glds; all reads of cur done
    }

    // epilogue: lacc rows (qd*4+r) match oacc rows directly — no reduce needed
    #pragma unroll
    for (int r = 0; r < 4; ++r) {
        const int irow = iw + qd * 4 + r;
        const float inv = 1.0f / lacc[r];
        #pragma unroll
        for (int nt = 0; nt < 4; ++nt)
            op[(size_t)irow * 1024 + nt * 16 + c] = f2bf(oacc[nt][r] * inv);
    }
}

// ---------------------------------------------------------------------------
// ws plan (peak 40 MiB):
//   kqv@0 (24M, natural [4096][3072] bf16)  vtr@24M (8M)
//   wt_attn@32M (6M, dead after gemm_qkv)  abuf@32M (8M, after wt_attn dead)
//   wt_proj@0 (2M, kqv dead after attn)
//   xb (bf16 x) staged in d_out (f32 out = 16 MB); dead before proj gemm.
// ---------------------------------------------------------------------------
extern "C" void kernel_launch(void* const* d_in, const int* in_sizes, int n_in,
                              void* d_out, int out_size, void* d_ws, size_t ws_size,
                              hipStream_t stream) {
    const void *px = nullptr, *paw = nullptr, *pab = nullptr, *ppw = nullptr, *ppb = nullptr;
    for (int i = 0; i < n_in; ++i) {
        switch (in_sizes[i]) {
            case 4194304: px  = d_in[i]; break;  // x [2,2048,1024] f32
            case 3145728: paw = d_in[i]; break;  // c_attn_w [1024,3072] f32
            case 3072:    pab = d_in[i]; break;  // c_attn_b f32
            case 1048576: ppw = d_in[i]; break;  // c_proj_w [1024,1024] f32
            case 1024:    ppb = d_in[i]; break;  // c_proj_b f32
        }
    }
    if (!px || !paw || !pab || !ppw || !ppb) return;

    char* ws = (char*)d_ws;
    u16* kqv     = (u16*)(ws);                 // [4096,3072] bf16  24 MB
    u16* vtr     = (u16*)(ws + 25165824);      // [2,16,64,2048]     8 MB
    u16* wt_attn = (u16*)(ws + 33554432);      // [3072,1024]        6 MB
    u16* abuf    = (u16*)(ws + 33554432);      // [4096,1024] bf16   8 MB (wt_attn dead)
    u16* wt_proj = (u16*)(ws);                 // [1024,1024]        2 MB (kqv dead)
    float* out   = (float*)d_out;              // [4096,1024] f32
    u16* xb      = (u16*)d_out;                // bf16 x staged in d_out

    f32_to_bf16<<<2048, 256, 0, stream>>>((const float*)px, xb);
    transpose_k<<<dim3(48, 16), 256, 0, stream>>>((const float*)paw, wt_attn, 1024, 3072);
    gemm_qkv<<<dim3(32, 24), 256, 0, stream>>>(xb, wt_attn, (const float*)pab, kqv);
    transpose_v<<<dim3(32, 32), 256, 0, stream>>>(kqv, vtr);
    attn_kernel<<<dim3(1024), 256, 0, stream>>>(kqv, vtr, abuf);
    transpose_k<<<dim3(16, 16), 256, 0, stream>>>((const float*)ppw, wt_proj, 1024, 1024);
    gemm_proj<<<dim3(32, 16), 256, 0, stream>>>(abuf, wt_proj, (const float*)ppb, out);
}

// Round 6
// 181.440 us; speedup vs baseline: 1.2634x; 1.0086x over previous
//
#include <hip/hip_runtime.h>
#include <hip/hip_bf16.h>

typedef unsigned short u16;
typedef unsigned int u32;
typedef __attribute__((ext_vector_type(8))) short bf16x8;
typedef __attribute__((ext_vector_type(4))) short bf16x4;
typedef __attribute__((ext_vector_type(4))) float f32x4;

#define MFMA_BF16(a, b, c) __builtin_amdgcn_mfma_f32_16x16x32_bf16((a), (b), (c), 0, 0, 0)

// 16x16x16 bf16 MFMA (CDNA2+ "1k" form; instruction present on gfx950 per ISA).
#if __has_builtin(__builtin_amdgcn_mfma_f32_16x16x16bf16_1k)
#define MFMA16(a, b, c) __builtin_amdgcn_mfma_f32_16x16x16bf16_1k((a), (b), (c), 0, 0, 0)
#define MFMA16_FENCE()
#else
__device__ __forceinline__ f32x4 mfma16_asm(bf16x4 a, bf16x4 b, f32x4 c) {
    f32x4 d;
    asm volatile("s_nop 1\n\tv_mfma_f32_16x16x16_bf16 %0, %1, %2, %3"
                 : "=v"(d) : "v"(a), "v"(b), "v"(c));
    return d;
}
#define MFMA16(a, b, c) mfma16_asm((a), (b), (c))
#define MFMA16_FENCE() asm volatile("s_nop 7\n\ts_nop 7")
#endif

__device__ __forceinline__ u16 f2bf(float f) {
    u32 u;
    __builtin_memcpy(&u, &f, 4);
    u += 0x7fffu + ((u >> 16) & 1u);
    return (u16)(u >> 16);
}

__device__ __forceinline__ void glds16(const void* g, void* l) {
    __builtin_amdgcn_global_load_lds(
        (__attribute__((address_space(1))) void*)(g),
        (__attribute__((address_space(3))) void*)(l),
        16, 0, 0);
}

// ---------------------------------------------------------------------------
// f32 -> bf16 elementwise convert; 8 elements per thread.
// ---------------------------------------------------------------------------
__global__ __launch_bounds__(256) void f32_to_bf16(const float* __restrict__ in,
                                                   u16* __restrict__ out) {
    const int i = blockIdx.x * 256 + threadIdx.x;
    const float4* p = (const float4*)in;
    float4 a = p[i * 2], b = p[i * 2 + 1];
    ushort4 lo, hi;
    lo.x = f2bf(a.x); lo.y = f2bf(a.y); lo.z = f2bf(a.z); lo.w = f2bf(a.w);
    hi.x = f2bf(b.x); hi.y = f2bf(b.y); hi.z = f2bf(b.z); hi.w = f2bf(b.w);
    *(ushort4*)&out[i * 8] = lo;
    *(ushort4*)&out[i * 8 + 4] = hi;
}

// ---------------------------------------------------------------------------
// Weight transpose + f32->bf16: in f32 [K][N] -> out bf16 [N][K]
// grid: (N/64, K/64), block 256
// ---------------------------------------------------------------------------
__global__ __launch_bounds__(256) void transpose_k(const float* __restrict__ in,
                                                   u16* __restrict__ out,
                                                   int K, int N) {
    __shared__ u16 tl[64][68];
    const int tid = threadIdx.x;
    const int n0 = blockIdx.x * 64, k0 = blockIdx.y * 64;
    #pragma unroll
    for (int it = 0; it < 4; ++it) {
        int idx = tid + it * 256;
        int r = idx >> 4, c4 = (idx & 15) * 4;
        float4 v = *(const float4*)&in[(size_t)(k0 + r) * N + n0 + c4];
        tl[r][c4 + 0] = f2bf(v.x); tl[r][c4 + 1] = f2bf(v.y);
        tl[r][c4 + 2] = f2bf(v.z); tl[r][c4 + 3] = f2bf(v.w);
    }
    __syncthreads();
    #pragma unroll
    for (int it = 0; it < 4; ++it) {
        int idx = tid + it * 256;
        int r = idx >> 4, c4 = (idx & 15) * 4;
        ushort4 v;
        v.x = tl[c4 + 0][r]; v.y = tl[c4 + 1][r];
        v.z = tl[c4 + 2][r]; v.w = tl[c4 + 3][r];
        *(ushort4*)&out[(size_t)(n0 + r) * K + k0 + c4] = v;
    }
}

// ---------------------------------------------------------------------------
// bf16 transpose for V: reads V band from natural kqv [4096][3072]
// (cols 2048 + h*64 ..) -> out [BH][D=64][T=2048]. grid (T/64, BH), block 256.
// ---------------------------------------------------------------------------
__global__ __launch_bounds__(256) void transpose_v(const u16* __restrict__ kqv,
                                                   u16* __restrict__ out) {
    __shared__ u16 tl[64][72];
    const int tid = threadIdx.x;
    const int t0 = blockIdx.x * 64;
    const int bh = blockIdx.y;
    const int b = bh >> 4, hh = bh & 15;
    const u16* ip = kqv + (size_t)b * 2048 * 3072 + 2048 + hh * 64;
    u16* op = out + (size_t)bh * 64 * 2048;
    #pragma unroll
    for (int it = 0; it < 2; ++it) {
        int idx = tid + it * 256;
        int r = idx >> 3, c8 = (idx & 7) * 8;
        *(bf16x8*)&tl[r][c8] = *(const bf16x8*)&ip[(size_t)(t0 + r) * 3072 + c8];
    }
    __syncthreads();
    #pragma unroll
    for (int it = 0; it < 2; ++it) {
        int idx = tid + it * 256;
        int d = idx >> 3, c8 = (idx & 7) * 8;
        ushort4 v0, v1;
        v0.x = tl[c8 + 0][d]; v0.y = tl[c8 + 1][d];
        v0.z = tl[c8 + 2][d]; v0.w = tl[c8 + 3][d];
        v1.x = tl[c8 + 4][d]; v1.y = tl[c8 + 5][d];
        v1.z = tl[c8 + 6][d]; v1.w = tl[c8 + 7][d];
        *(ushort4*)&op[(size_t)d * 2048 + t0 + c8] = v0;
        *(ushort4*)&op[(size_t)d * 2048 + t0 + c8 + 4] = v1;
    }
}

// ---------------------------------------------------------------------------
// QKV GEMM, 2-phase double-buffered (T3-minimum): C[4096,3072] natural bf16.
// BM=BN=128, BK=32, 4 waves 2x2. Next K-tile staged via glds16 BEFORE the
// current tile's ds_read+MFMA; ONE barrier/iter. LDS chunk swizzle via
// pre-swizzled glds16 SOURCE (linear dest, rule 21); read side same XOR.
// K cols (<1024) pre-scaled by log2(e)/sqrt(64). LDS 32 KB -> 3 blocks/CU.
// ---------------------------------------------------------------------------
__global__ __launch_bounds__(256) void gemm_qkv(const u16* __restrict__ A,
                                                const u16* __restrict__ BT,
                                                const float* __restrict__ bias,
                                                u16* __restrict__ out) {
    __shared__ u16 As[2][128 * 32];
    __shared__ u16 Bs[2][128 * 32];
    const int tid = threadIdx.x;
    const int w = tid >> 6, lane = tid & 63;
    const int c = lane & 15, qd = lane >> 4;
    const int wm = (w >> 1) * 64, wn = (w & 1) * 64;
    const int bm = blockIdx.x * 128, bn = blockIdx.y * 128;
    const int K = 1024;

    f32x4 acc[4][4];
    #pragma unroll
    for (int mt = 0; mt < 4; ++mt)
        #pragma unroll
        for (int nt = 0; nt < 4; ++nt)
            acc[mt][nt] = (f32x4){0.f, 0.f, 0.f, 0.f};

    // staging: thread -> (row = tid>>2 [+64], src chunk swizzled by (row>>1)&3)
    const int srow = tid >> 2;
    const int schk8 = ((tid & 3) ^ ((tid >> 3) & 3)) * 8;
    const u16* aP = A + (size_t)(bm + srow) * K + schk8;
    const u16* bP = BT + (size_t)(bn + srow) * K + schk8;
    const int rk = (c >> 1) & 3;          // read-side xor key

    // prologue: stage K-tile 0 into buffer 0
    glds16(aP, &As[0][tid * 8]);
    glds16(aP + 64 * K, &As[0][2048 + tid * 8]);
    glds16(bP, &Bs[0][tid * 8]);
    glds16(bP + 64 * K, &Bs[0][2048 + tid * 8]);
    __syncthreads();

    for (int kk = 0; kk < K; kk += 32) {
        const int cur = (kk >> 5) & 1;
        if (kk + 32 < K) {               // prefetch next K-tile into other buf
            const int nb = cur ^ 1;
            glds16(aP + kk + 32, &As[nb][tid * 8]);
            glds16(aP + kk + 32 + 64 * K, &As[nb][2048 + tid * 8]);
            glds16(bP + kk + 32, &Bs[nb][tid * 8]);
            glds16(bP + kk + 32 + 64 * K, &Bs[nb][2048 + tid * 8]);
        }
        bf16x8 af[4], bfr[4];
        #pragma unroll
        for (int mt = 0; mt < 4; ++mt)
            af[mt] = *(const bf16x8*)&As[cur][(wm + mt * 16 + c) * 32 + ((qd ^ rk) << 3)];
        #pragma unroll
        for (int nt = 0; nt < 4; ++nt)
            bfr[nt] = *(const bf16x8*)&Bs[cur][(wn + nt * 16 + c) * 32 + ((qd ^ rk) << 3)];
        #pragma unroll
        for (int mt = 0; mt < 4; ++mt)
            #pragma unroll
            for (int nt = 0; nt < 4; ++nt)
                acc[mt][nt] = MFMA_BF16(af[mt], bfr[nt], acc[mt][nt]);
        __syncthreads();                 // drains prefetch vmcnt + read lgkm
    }

    #pragma unroll
    for (int nt = 0; nt < 4; ++nt) {
        const int coln = bn + wn + nt * 16 + c;
        const float bv = bias[coln];
        // fold attention scale log2(e)/sqrt(64) into K (cols < 1024)
        const float kscl = (coln < 1024) ? 0.18033688f : 1.0f;
        #pragma unroll
        for (int mt = 0; mt < 4; ++mt)
            #pragma unroll
            for (int r = 0; r < 4; ++r) {
                const int row = bm + wm + mt * 16 + qd * 4 + r;
                out[(size_t)row * 3072 + coln] = f2bf((acc[mt][nt][r] + bv) * kscl);
            }
    }
}

// ---------------------------------------------------------------------------
// Proj GEMM: C[4096,1024] f32 = A[4096,1024]*BT[1024,1024]^T + bias.
// BM=128, BN=64 -> grid 32x16 = 512 blocks = 2 blocks/CU. 4 waves 4Mx1N.
// Same dbuf + swizzle structure as gemm_qkv. LDS 24 KB.
// ---------------------------------------------------------------------------
__global__ __launch_bounds__(256) void gemm_proj(const u16* __restrict__ A,
                                                 const u16* __restrict__ BT,
                                                 const float* __restrict__ bias,
                                                 float* __restrict__ outf) {
    __shared__ u16 As[2][128 * 32];
    __shared__ u16 Bs[2][64 * 32];
    const int tid = threadIdx.x;
    const int w = tid >> 6, lane = tid & 63;
    const int c = lane & 15, qd = lane >> 4;
    const int wm = w * 32;
    const int bm = blockIdx.x * 128, bn = blockIdx.y * 64;
    const int K = 1024;

    f32x4 acc[2][4];
    #pragma unroll
    for (int mt = 0; mt < 2; ++mt)
        #pragma unroll
        for (int nt = 0; nt < 4; ++nt)
            acc[mt][nt] = (f32x4){0.f, 0.f, 0.f, 0.f};

    const int srow = tid >> 2;
    const int schk8 = ((tid & 3) ^ ((tid >> 3) & 3)) * 8;
    const u16* aP = A + (size_t)(bm + srow) * K + schk8;
    const u16* bP = BT + (size_t)(bn + srow) * K + schk8;
    const int rk = (c >> 1) & 3;

    glds16(aP, &As[0][tid * 8]);
    glds16(aP + 64 * K, &As[0][2048 + tid * 8]);
    glds16(bP, &Bs[0][tid * 8]);
    __syncthreads();

    for (int kk = 0; kk < K; kk += 32) {
        const int cur = (kk >> 5) & 1;
        if (kk + 32 < K) {
            const int nb = cur ^ 1;
            glds16(aP + kk + 32, &As[nb][tid * 8]);
            glds16(aP + kk + 32 + 64 * K, &As[nb][2048 + tid * 8]);
            glds16(bP + kk + 32, &Bs[nb][tid * 8]);
        }
        bf16x8 af[2], bfr[4];
        #pragma unroll
        for (int mt = 0; mt < 2; ++mt)
            af[mt] = *(const bf16x8*)&As[cur][(wm + mt * 16 + c) * 32 + ((qd ^ rk) << 3)];
        #pragma unroll
        for (int nt = 0; nt < 4; ++nt)
            bfr[nt] = *(const bf16x8*)&Bs[cur][(nt * 16 + c) * 32 + ((qd ^ rk) << 3)];
        #pragma unroll
        for (int mt = 0; mt < 2; ++mt)
            #pragma unroll
            for (int nt = 0; nt < 4; ++nt)
                acc[mt][nt] = MFMA_BF16(af[mt], bfr[nt], acc[mt][nt]);
        __syncthreads();
    }

    #pragma unroll
    for (int nt = 0; nt < 4; ++nt) {
        const int coln = bn + nt * 16 + c;
        const float bv = bias[coln];
        #pragma unroll
        for (int mt = 0; mt < 2; ++mt)
            #pragma unroll
            for (int r = 0; r < 4; ++r) {
                const int row = bm + wm + mt * 16 + qd * 4 + r;
                outf[(size_t)row * 1024 + coln] = acc[mt][nt][r] + bv;
            }
    }
}

// ---------------------------------------------------------------------------
// MFMA flash attention v9. wei = K@Q^T (K rows = queries). K pre-scaled.
// v8 diagnosis: LDS pipe saturated (qf+pf+vf+Ps ~230cyc/wave-tile vs 87 MFMA)
// and the Ps write->read round-trip is serial inside every tile.
// v9: P NEVER touches LDS. Layout identity: QK^T D-frag (i=l&15, j=qd*4+r)
// IS the A-frag of v_mfma 16x16x16 (m=l&15, k=qd*4+e). exp2'd P packs to
// bf16x4 in regs and feeds PV directly; PV = 16x16x16 MFMA, B = V read as
// b64 from swizzled Vb [d][j] (4 contiguous j per lane). l via ones-B
// 16x16x16 MFMA per jt -> same D row layout (i=qd*4+r) as oacc; epilogue
// unchanged. Ps/psw deleted: LDS 32768 B exactly -> up to 5 blocks/CU.
// 1024 blocks (32 ib x 32 bh), longest-first, XCD-grouped bh decode.
// ---------------------------------------------------------------------------
__global__ __launch_bounds__(256, 4) void attn_kernel(const u16* __restrict__ kqv,
                                                      const u16* __restrict__ vtbuf,
                                                      u16* __restrict__ outb) {
    __shared__ __align__(16) u16 Qb[2][64 * 64];
    __shared__ __align__(16) u16 Vb[2][64 * 64];

    const int tid = threadIdx.x;
    const int w = tid >> 6, lane = tid & 63;
    const int c = lane & 15, qd = lane >> 4;
    // decode: xcd = f&7 hosts bh in [xcd*4, xcd*4+4); ib descending in time
    const int f = blockIdx.x;
    const int bh = (f & 7) * 4 + ((f >> 3) & 3);
    const int ib = 31 - (f >> 5);       // longest blocks dispatch first
    const int b = bh >> 4, hh = bh & 15;
    const u16* kp = kqv + (size_t)b * 2048 * 3072 + hh * 64;          // k band
    const u16* qp = kqv + (size_t)b * 2048 * 3072 + 1024 + hh * 64;   // q band
    const u16* vp = vtbuf + (size_t)bh * (64 * 2048);
    u16* op = outb + (size_t)b * (2048 * 1024) + hh * 64;
    const f32x4 zero4 = {0.f, 0.f, 0.f, 0.f};

    // staging geometry: thread covers slots (w*128+lane) and (+64); 8 rows/8 col8
    const int slot0 = w * 128 + lane;
    const int slot1 = slot0 + 64;
    const int r0 = slot0 >> 3, r1 = slot1 >> 3;            // r1 = r0 + 8
    const int c8g = ((lane & 7) ^ ((lane >> 3) & 7)) * 8;  // swizzled src col
    const int swz = (c & 7);                               // read-side xor key

    const int nj = ib + 1;
    const int iw = ib * 64 + w * 16;                       // wave's 16 i-rows

    // K fragments direct from global (2 KB/wave, read once per block)
    bf16x8 kf[2];
    #pragma unroll
    for (int kt = 0; kt < 2; ++kt)
        kf[kt] = *(const bf16x8*)&kp[(size_t)(iw + c) * 3072 + kt * 32 + qd * 8];

    // all-ones bf16x4 B-fragment for the l row-sum MFMA16
    bf16x4 ones4;
    #pragma unroll
    for (int e = 0; e < 4; ++e) ones4[e] = (short)0x3F80;

    f32x4 oacc[4];
    #pragma unroll
    for (int nt = 0; nt < 4; ++nt)
        oacc[nt] = zero4;
    f32x4 lacc = zero4;

    // prologue: stage tile 0 into buffer 0
    glds16(qp + (size_t)r0 * 3072 + c8g, &Qb[0][slot0 * 8]);
    glds16(qp + (size_t)r1 * 3072 + c8g, &Qb[0][slot1 * 8]);
    glds16(vp + (size_t)r0 * 2048 + c8g, &Vb[0][slot0 * 8]);
    glds16(vp + (size_t)r1 * 2048 + c8g, &Vb[0][slot1 * 8]);
    __syncthreads();

    for (int jj = 0; jj < nj; ++jj) {
        const int cur = jj & 1;
        if (jj + 1 < nj) {              // async-prefetch next tile
            const int jn = (jj + 1) * 64;
            const int nb = cur ^ 1;
            glds16(qp + (size_t)(jn + r0) * 3072 + c8g, &Qb[nb][slot0 * 8]);
            glds16(qp + (size_t)(jn + r1) * 3072 + c8g, &Qb[nb][slot1 * 8]);
            glds16(vp + (size_t)r0 * 2048 + jn + c8g, &Vb[nb][slot0 * 8]);
            glds16(vp + (size_t)r1 * 2048 + jn + c8g, &Vb[nb][slot1 * 8]);
        }
        const int j0 = jj * 64;

        // S^T[j][i]: A = Q rows j (4 jt), B = kf (wave's 16 i-rows)
        bf16x8 qf[4][2];
        #pragma unroll
        for (int jt = 0; jt < 4; ++jt)
            #pragma unroll
            for (int kt = 0; kt < 2; ++kt)
                qf[jt][kt] = *(const bf16x8*)&Qb[cur][(jt * 16 + c) * 64 + (((kt * 4 + qd) ^ swz) << 3)];
        f32x4 sacc[4];
        __builtin_amdgcn_s_setprio(1);
        #pragma unroll
        for (int jt = 0; jt < 4; ++jt) {
            f32x4 s0 = zero4;
            s0 = MFMA_BF16(qf[jt][0], kf[0], s0);
            s0 = MFMA_BF16(qf[jt][1], kf[1], s0);
            sacc[jt] = s0;
        }
        __builtin_amdgcn_s_setprio(0);

        if (jj == nj - 1) {   // diagonal tile: causal mask, valid iff j <= i
            #pragma unroll
            for (int jt = 0; jt < 4; ++jt)
                #pragma unroll
                for (int r = 0; r < 4; ++r) {
                    int j = j0 + jt * 16 + qd * 4 + r;
                    int i = iw + c;
                    if (j > i) sacc[jt][r] = -3.0e38f;
                }
        }

        // static-max softmax; P packed to bf16x4 A-frags IN REGISTERS.
        // Lane holds (i = l&15, j-slice = qd*4+e) == 16x16x16 A layout.
        bf16x4 pa[4];
        #pragma unroll
        for (int jt = 0; jt < 4; ++jt) {
            float p0 = exp2f(sacc[jt][0]);
            float p1 = exp2f(sacc[jt][1]);
            float p2 = exp2f(sacc[jt][2]);
            float p3 = exp2f(sacc[jt][3]);
            u32 b0, b1, b2, b3;
            __builtin_memcpy(&b0, &p0, 4);
            __builtin_memcpy(&b1, &p1, 4);
            __builtin_memcpy(&b2, &p2, 4);
            __builtin_memcpy(&b3, &p3, 4);
            u32 t[2];
            t[0] = __builtin_amdgcn_perm(b1 + 0x8000u, b0 + 0x8000u, 0x07060302u);
            t[1] = __builtin_amdgcn_perm(b3 + 0x8000u, b2 + 0x8000u, 0x07060302u);
            __builtin_memcpy(&pa[jt], t, 8);
        }

        // O[i][d] += P[i][j] * V[j][d] via 16x16x16 (B = 4 contiguous j of Vb
        // row d, b64, swizzle-corrected); l[i] += row-sum via ones-B MFMA16.
        __builtin_amdgcn_s_setprio(1);
        #pragma unroll
        for (int jt = 0; jt < 4; ++jt) {
            lacc = MFMA16(pa[jt], ones4, lacc);
            #pragma unroll
            for (int nt = 0; nt < 4; ++nt) {
                const bf16x4 vf = *(const bf16x4*)&Vb[cur][(nt * 16 + c) * 64 +
                    (((jt * 2 + (qd >> 1)) ^ swz) << 3) + (qd & 1) * 4];
                oacc[nt] = MFMA16(pa[jt], vf, oacc[nt]);
            }
        }
        __builtin_amdgcn_s_setprio(0);
        __syncthreads();   // drains prefetch glds; all reads of cur done
    }

    MFMA16_FENCE();
    // epilogue: lacc rows (qd*4+r) match oacc rows directly — no reduce needed
    #pragma unroll
    for (int r = 0; r < 4; ++r) {
        const int irow = iw + qd * 4 + r;
        const float inv = 1.0f / lacc[r];
        #pragma unroll
        for (int nt = 0; nt < 4; ++nt)
            op[(size_t)irow * 1024 + nt * 16 + c] = f2bf(oacc[nt][r] * inv);
    }
}

// ---------------------------------------------------------------------------
// ws plan (peak 40 MiB):
//   kqv@0 (24M, natural [4096][3072] bf16)  vtr@24M (8M)
//   wt_attn@32M (6M, dead after gemm_qkv)  abuf@32M (8M, after wt_attn dead)
//   wt_proj@0 (2M, kqv dead after attn)
//   xb (bf16 x) staged in d_out (f32 out = 16 MB); dead before proj gemm.
// ---------------------------------------------------------------------------
extern "C" void kernel_launch(void* const* d_in, const int* in_sizes, int n_in,
                              void* d_out, int out_size, void* d_ws, size_t ws_size,
                              hipStream_t stream) {
    const void *px = nullptr, *paw = nullptr, *pab = nullptr, *ppw = nullptr, *ppb = nullptr;
    for (int i = 0; i < n_in; ++i) {
        switch (in_sizes[i]) {
            case 4194304: px  = d_in[i]; break;  // x [2,2048,1024] f32
            case 3145728: paw = d_in[i]; break;  // c_attn_w [1024,3072] f32
            case 3072:    pab = d_in[i]; break;  // c_attn_b f32
            case 1048576: ppw = d_in[i]; break;  // c_proj_w [1024,1024] f32
            case 1024:    ppb = d_in[i]; break;  // c_proj_b f32
        }
    }
    if (!px || !paw || !pab || !ppw || !ppb) return;

    char* ws = (char*)d_ws;
    u16* kqv     = (u16*)(ws);                 // [4096,3072] bf16  24 MB
    u16* vtr     = (u16*)(ws + 25165824);      // [2,16,64,2048]     8 MB
    u16* wt_attn = (u16*)(ws + 33554432);      // [3072,1024]        6 MB
    u16* abuf    = (u16*)(ws + 33554432);      // [4096,1024] bf16   8 MB (wt_attn dead)
    u16* wt_proj = (u16*)(ws);                 // [1024,1024]        2 MB (kqv dead)
    float* out   = (float*)d_out;              // [4096,1024] f32
    u16* xb      = (u16*)d_out;                // bf16 x staged in d_out

    f32_to_bf16<<<2048, 256, 0, stream>>>((const float*)px, xb);
    transpose_k<<<dim3(48, 16), 256, 0, stream>>>((const float*)paw, wt_attn, 1024, 3072);
    gemm_qkv<<<dim3(32, 24), 256, 0, stream>>>(xb, wt_attn, (const float*)pab, kqv);
    transpose_v<<<dim3(32, 32), 256, 0, stream>>>(kqv, vtr);
    attn_kernel<<<dim3(1024), 256, 0, stream>>>(kqv, vtr, abuf);
    transpose_k<<<dim3(16, 16), 256, 0, stream>>>((const float*)ppw, wt_proj, 1024, 1024);
    gemm_proj<<<dim3(32, 16), 256, 0, stream>>>(abuf, wt_proj, (const float*)ppb, out);
}